// Round 20
// baseline (135.355 us; speedup 1.0000x reference)
//
#include <hip/hip_runtime.h>
#include <float.h>

#define B_   8
#define C_   64
#define N_   4096
#define OUT_ 128
#define KNN  9
#define CAP  64          // per-quarter append capacity (overflow -> exact fallback)
#define TAU_A 2.15f      // threshold: tau = TAU_A*sigma_n - 64

typedef __attribute__((ext_vector_type(8))) short short8;
typedef __attribute__((ext_vector_type(4))) float f32x4;

__device__ inline unsigned short f2bf(float f) {
    unsigned u = __float_as_uint(f);
    unsigned r = (u + 0x7fffu + ((u >> 16) & 1u)) >> 16;
    return (unsigned short)r;
}
__device__ inline float bf2f(unsigned short s) {
    return __uint_as_float(((unsigned)s) << 16);
}

// ---------------------------------------------------------------------------
// ws layout (bytes):
//   xT:     [B][N][C] float    @ 0          (8388608)
//   xfrag:  hi bf16 chunks     @ 8388608    (4194304)  } idx9 aliases xfrag
//   idx9:   [B*N][9]  int      @ 8388608    (1179648)  } (xfrag dead by refine)
//   x2:     [B][N]    float    @ 16777216   (131072)
//   wfrag:  W hi/lo bf16 frags @ 16908288   (65536)
//   cand48: [B*N][48] u32      @ 16973824   (6291456)  packed (key20|idx12)
//   cnt4:   [B*N][4]  int      @ 23265280   (524288)   total ~23.8 MB
//
// HARD-WON CONSTRAINTS:
//  - (R12,R16) launch_bounds waves/EU >= 8 caps VGPR at 32 -> scan spills.
//    Use waves/EU == 4 (VGPR cap 64; body measures ~40).
//  - (R18) fullscan fallback must be a SEPARATE early-exit kernel (reg pressure).
// ---------------------------------------------------------------------------

// transpose + x2 + bf16-hi x-fragment build; blocks 512..519 build W frags.
__global__ void k_transpose(const float* __restrict__ x, float* __restrict__ xT,
                            float* __restrict__ x2, unsigned short* __restrict__ xfrag,
                            const float* __restrict__ W, unsigned short* __restrict__ wfrag) {
    __shared__ float t[C_][65];
    int tid = threadIdx.x;
    if (blockIdx.x >= 512) {                     // merged k_wt
        int mt = blockIdx.x - 512;
        int kc = tid >> 6, L = tid & 63;
        int o  = mt * 16 + (L & 15);
        int c0 = kc * 32 + ((L >> 4) * 8);
        const float* src = W + (size_t)o * 128 + c0;
        float4 v0 = *(const float4*)src, v1 = *(const float4*)(src + 4);
        float vs[8] = {v0.x, v0.y, v0.z, v0.w, v1.x, v1.y, v1.z, v1.w};
        short8 hi, lo;
#pragma unroll
        for (int j = 0; j < 8; ++j) {
            unsigned short hb = f2bf(vs[j]);
            float hf = bf2f(hb);
            lo[j] = (short)f2bf(vs[j] - hf);
            hi[j] = (short)hb;
        }
        size_t cb = (size_t)(mt * 4 + kc) * 2 * 512;   // ushort units
        *(short8*)(wfrag + cb + L * 8)       = hi;
        *(short8*)(wfrag + cb + 512 + L * 8) = lo;
        return;
    }
    int b  = blockIdx.x & 7;                     // XCD-pinned batch
    int n0 = (blockIdx.x >> 3) * 64;
    for (int i = 0; i < 4; ++i) {
        int f = i * 256 + tid;
        int c = f >> 4, n4 = f & 15;
        float4 v = *(const float4*)(x + ((size_t)b * C_ + c) * N_ + n0 + n4 * 4);
        t[c][n4 * 4 + 0] = v.x;
        t[c][n4 * 4 + 1] = v.y;
        t[c][n4 * 4 + 2] = v.z;
        t[c][n4 * 4 + 3] = v.w;
    }
    __syncthreads();
    for (int i = 0; i < 4; ++i) {
        int f = i * 256 + tid;
        int n = f >> 4, c4 = f & 15;
        float4 v = {t[c4 * 4 + 0][n], t[c4 * 4 + 1][n],
                    t[c4 * 4 + 2][n], t[c4 * 4 + 3][n]};
        *(float4*)(xT + ((size_t)b * N_ + n0 + n) * C_ + c4 * 4) = v;
    }
    int q = tid >> 6, L = tid & 63;
    int mloc = q * 16 + (L & 15);
    int k8 = (L >> 4) * 8;
    size_t cb = (size_t)(b * 256 + (n0 >> 4) + q) * 2 * 512;   // ushort units
#pragma unroll
    for (int h = 0; h < 2; ++h) {
        short8 hi;
#pragma unroll
        for (int j = 0; j < 8; ++j)
            hi[j] = (short)f2bf(t[h * 32 + k8 + j][mloc]);
        *(short8*)(xfrag + cb + h * 512 + L * 8) = hi;
    }
    if (tid < 64) {
        float s = 0.f;
        for (int c = 0; c < C_; ++c) { float v = t[c][tid]; s += v * v; }
        x2[(size_t)b * N_ + n0 + tid] = s;
    }
}

// append packed (20-bit sortable key | 12-bit index)
#define APPEND(KEY, TAU, LN, MIDX)                                      \
    if ((KEY) > (TAU)) {                                                \
        unsigned u = __float_as_uint(KEY);                              \
        u = (u & 0x80000000u) ? ~u : (u | 0x80000000u);                 \
        unsigned pk = (u & 0xFFFFF000u) | (unsigned)(MIDX);             \
        int sl = atomicAdd(&cnt_s[LN], 1);                              \
        if (sl < CAP) buf_s[LN][sl] = pk;                               \
    }

// MFMA scan (bf16-hi) + threshold compaction + in-LDS per-quarter top-12.
// grid 2048: b = blk&7 (XCD-pinned), mq = (blk>>3)&3, ng = blk>>5.
// 256 threads = 4 waves; wave w scans m-tiles [mq*64 + w*16, +16).
// lb(256,4): VGPR cap 64 (body ~40, NO spill); 8 blocks/CU x 4 waves possible.
__global__ __launch_bounds__(256, 4) void k_topk_mf(const unsigned short* __restrict__ xfrag,
                                                    const float* __restrict__ x2,
                                                    unsigned* __restrict__ cand48,
                                                    int* __restrict__ cnt4) {
    __shared__ int cnt_s[64];
    __shared__ unsigned buf_s[64][CAP];
    int b    = blockIdx.x & 7;
    int mq   = (blockIdx.x >> 3) & 3;
    int ng   = blockIdx.x >> 5;                  // 0..63
    int wave = threadIdx.x >> 6, lane = threadIdx.x & 63;
    if (threadIdx.x < 64) cnt_s[threadIdx.x] = 0;

    const short8* fr = (const short8*)xfrag;     // 16B units; chunk = 64 short8

    short8 Bh[4][2];
#pragma unroll
    for (int q = 0; q < 4; ++q)
#pragma unroll
        for (int h = 0; h < 2; ++h) {
            int ch = ((b * 256 + ng * 4 + q) * 2 + h);
            Bh[q][h] = fr[(size_t)ch * 64 + lane];
        }

    float tau[4];
#pragma unroll
    for (int q = 0; q < 4; ++q) {
        float x2n = x2[b * N_ + ng * 64 + q * 16 + (lane & 15)];
        tau[q] = TAU_A * sqrtf(fmaf(4.f, x2n, 128.f)) - 64.f;
    }

    int mt0 = mq * 64 + wave * 16;               // m-tile start (16 tiles per wave)
    const short8* pA = fr + (size_t)(b * 256 + mt0) * 2 * 64 + lane;
    const f32x4*  px2 = (const f32x4*)(x2 + b * N_ + mt0 * 16 + (lane >> 4) * 4);
    short8 Ah0 = pA[0], Ah1 = pA[64];
    f32x4 x2v = *px2;

    __syncthreads();   // cnt_s zeroed

    for (int i = 0; i < 16; ++i) {
        if (i != 15) { pA += 128; px2 += 4; }
        short8 nAh0 = pA[0], nAh1 = pA[64];
        f32x4 nx2 = *px2;

        int mbase = (mt0 + i) * 16 + (lane >> 4) * 4;

#pragma unroll
        for (int q = 0; q < 4; ++q) {
            f32x4 acc = {0.f, 0.f, 0.f, 0.f};
            acc = __builtin_amdgcn_mfma_f32_16x16x32_bf16(Ah0, Bh[q][0], acc, 0, 0, 0);
            acc = __builtin_amdgcn_mfma_f32_16x16x32_bf16(Ah1, Bh[q][1], acc, 0, 0, 0);
            float k0 = fmaf(2.f, acc[0], -x2v[0]);
            float k1 = fmaf(2.f, acc[1], -x2v[1]);
            float k2 = fmaf(2.f, acc[2], -x2v[2]);
            float k3 = fmaf(2.f, acc[3], -x2v[3]);
            float kmax = fmaxf(fmaxf(k0, k1), fmaxf(k2, k3));
            if (kmax > tau[q]) {
                int ln = q * 16 + (lane & 15);
                APPEND(k0, tau[q], ln, mbase + 0)
                APPEND(k1, tau[q], ln, mbase + 1)
                APPEND(k2, tau[q], ln, mbase + 2)
                APPEND(k3, tau[q], ln, mbase + 3)
            }
        }
        Ah0 = nAh0; Ah1 = nAh1; x2v = nx2;
    }

    __syncthreads();
    if (threadIdx.x < 64) {
        int r = threadIdx.x;
        int c = cnt_s[r];
        size_t grow = (size_t)b * N_ + ng * 64 + r;
        cnt4[grow * 4 + mq] = c;
        int cc = min(c, CAP);
        unsigned best[12];
#pragma unroll
        for (int j = 0; j < 12; ++j) best[j] = 0u;
        for (int s = 0; s < cc; ++s) {
            unsigned v = buf_s[r][s];
            if (v > best[0]) {
                best[0] = v;
#pragma unroll
                for (int j = 0; j < 11; ++j) {
                    bool sw = best[j] > best[j + 1];
                    unsigned t = best[j];
                    best[j]     = sw ? best[j + 1] : best[j];
                    best[j + 1] = sw ? t : best[j + 1];
                }
            }
        }
#pragma unroll
        for (int j = 0; j < 12; ++j)
            cand48[grow * 48 + mq * 12 + j] = best[11 - j];
    }
}

// exact fp64 re-rank of up to 48 coarse candidates -> true top-9.
// Wave per row; rank-counting selection (R15-proven).
__global__ __launch_bounds__(256) void k_refine(const float* __restrict__ xT,
                                                const unsigned* __restrict__ cand48,
                                                const int* __restrict__ cnt4,
                                                int* __restrict__ idx9) {
    __shared__ double kk[4][48];
    __shared__ int    ki[4][48];
    int wave = threadIdx.x >> 6, lane = threadIdx.x & 63;
    int b = blockIdx.x & 7;
    int row = b * N_ + (blockIdx.x >> 3) * 4 + wave;
    int c0 = cnt4[(size_t)row * 4 + 0];
    int c1 = cnt4[(size_t)row * 4 + 1];
    int c2 = cnt4[(size_t)row * 4 + 2];
    int c3 = cnt4[(size_t)row * 4 + 3];
    int cmax = max(max(c0, c1), max(c2, c3));
    bool ok = (c0 + c1 + c2 + c3 >= KNN) && (cmax <= CAP);
    int qq = lane / 12, slot = lane - qq * 12;   // lane<48 -> quarter/slot
    int cq = (qq == 0) ? c0 : (qq == 1) ? c1 : (qq == 2) ? c2 : c3;

    double mykey = -1e300; int myidx = 0x7fffffff;
    bool valid = ok && (lane < 48) && (slot < min(cq, 12));
    if (valid) {
        int m = (int)(cand48[(size_t)row * 48 + lane] & 0xFFFu);
        const float* xi = xT + (size_t)row * C_;               // broadcast loads
        const float* xm = xT + (((size_t)b << 12) + m) * C_;   // per-lane stream
        double d0 = 0.0, d1 = 0.0, s0 = 0.0, s1 = 0.0;
#pragma unroll
        for (int c4 = 0; c4 < 16; c4 += 2) {
            float4 a0 = *(const float4*)(xi + c4 * 4);
            float4 a1 = *(const float4*)(xi + c4 * 4 + 4);
            float4 v0 = *(const float4*)(xm + c4 * 4);
            float4 v1 = *(const float4*)(xm + c4 * 4 + 4);
            d0 = fma((double)a0.x, (double)v0.x, d0);  s0 = fma((double)v0.x, (double)v0.x, s0);
            d0 = fma((double)a0.y, (double)v0.y, d0);  s0 = fma((double)v0.y, (double)v0.y, s0);
            d0 = fma((double)a0.z, (double)v0.z, d0);  s0 = fma((double)v0.z, (double)v0.z, s0);
            d0 = fma((double)a0.w, (double)v0.w, d0);  s0 = fma((double)v0.w, (double)v0.w, s0);
            d1 = fma((double)a1.x, (double)v1.x, d1);  s1 = fma((double)v1.x, (double)v1.x, s1);
            d1 = fma((double)a1.y, (double)v1.y, d1);  s1 = fma((double)v1.y, (double)v1.y, s1);
            d1 = fma((double)a1.z, (double)v1.z, d1);  s1 = fma((double)v1.z, (double)v1.z, s1);
            d1 = fma((double)a1.w, (double)v1.w, d1);  s1 = fma((double)v1.w, (double)v1.w, s1);
        }
        mykey = 2.0 * (d0 + d1) - (s0 + s1);
        myidx = m;
    }
    if (lane < 48) { kk[wave][lane] = mykey; ki[wave][lane] = myidx; }
    // same-wave LDS write->read: in-order per wave, lgkmcnt handled by compiler.
    if (valid) {
        int r = 0;
#pragma unroll
        for (int k = 0; k < 48; ++k) {
            double ok2 = kk[wave][k]; int oi = ki[wave][k];
            r += (ok2 > mykey || (ok2 == mykey && oi < myidx)) ? 1 : 0;
        }
        if (r < KNN) idx9[(size_t)row * KNN + r] = myidx;   // ranks distinct (idx unique)
    }
}

// exact fp64 full scan for rows where the threshold buffers failed (insurance).
// SEPARATE kernel: its register cost must not touch refine's occupancy (R18).
__global__ void k_fallback(const float* __restrict__ xT, const int* __restrict__ cnt4,
                           int* __restrict__ idx9) {
    int wave = threadIdx.x >> 6, lane = threadIdx.x & 63;
    int row = blockIdx.x * 4 + wave;
    int c0 = cnt4[(size_t)row * 4 + 0];
    int c1 = cnt4[(size_t)row * 4 + 1];
    int c2 = cnt4[(size_t)row * 4 + 2];
    int c3 = cnt4[(size_t)row * 4 + 3];
    int cmax = max(max(c0, c1), max(c2, c3));
    if ((c0 + c1 + c2 + c3 >= KNN) && (cmax <= CAP)) return;
    int b = row >> 12;
    const float* xi = xT + (size_t)row * C_;
    float4 xr[16];
#pragma unroll
    for (int c4 = 0; c4 < 16; ++c4) xr[c4] = *(const float4*)(xi + c4 * 4);
    double sk[9]; int si[9];
#pragma unroll
    for (int j = 0; j < 9; ++j) { sk[j] = -1e300; si[j] = 0x7fffffff; }
    for (int mb = 0; mb < N_; mb += 64) {
        int m = mb + lane;
        const float* xm = xT + (((size_t)b << 12) + m) * C_;
        double d0 = 0.0, d1 = 0.0, s0 = 0.0, s1 = 0.0;
#pragma unroll
        for (int c4 = 0; c4 < 16; c4 += 2) {
            float4 v = *(const float4*)(xm + c4 * 4);
            float4 w = *(const float4*)(xm + c4 * 4 + 4);
            float4 a = xr[c4], bb = xr[c4 + 1];
            d0 = fma((double)a.x, (double)v.x, d0);  s0 = fma((double)v.x, (double)v.x, s0);
            d0 = fma((double)a.y, (double)v.y, d0);  s0 = fma((double)v.y, (double)v.y, s0);
            d0 = fma((double)a.z, (double)v.z, d0);  s0 = fma((double)v.z, (double)v.z, s0);
            d0 = fma((double)a.w, (double)v.w, d0);  s0 = fma((double)v.w, (double)v.w, s0);
            d1 = fma((double)bb.x, (double)w.x, d1); s1 = fma((double)w.x, (double)w.x, s1);
            d1 = fma((double)bb.y, (double)w.y, d1); s1 = fma((double)w.y, (double)w.y, s1);
            d1 = fma((double)bb.z, (double)w.z, d1); s1 = fma((double)w.z, (double)w.z, s1);
            d1 = fma((double)bb.w, (double)w.w, d1); s1 = fma((double)w.w, (double)w.w, s1);
        }
        double key = 2.0 * (d0 + d1) - (s0 + s1);
        if (key > sk[0] || (key == sk[0] && m < si[0])) {
            sk[0] = key; si[0] = m;
#pragma unroll
            for (int j = 0; j < 8; ++j) {
                bool sw = (sk[j] > sk[j + 1]) || (sk[j] == sk[j + 1] && si[j] < si[j + 1]);
                double tk = sk[j]; int ti = si[j];
                sk[j]     = sw ? sk[j + 1] : sk[j];
                si[j]     = sw ? si[j + 1] : si[j];
                sk[j + 1] = sw ? tk : sk[j + 1];
                si[j + 1] = sw ? ti : si[j + 1];
            }
        }
    }
    for (int r = 0; r < KNN; ++r) {
        double k = sk[8]; int ix = si[8];
#pragma unroll
        for (int o = 32; o; o >>= 1) {
            double ok = __shfl_xor(k, o); int oi = __shfl_xor(ix, o);
            bool take = (ok > k) || (ok == k && oi < ix);
            k = take ? ok : k; ix = take ? oi : ix;
        }
        if (lane == 0) idx9[(size_t)row * KNN + r] = ix;
        if (si[8] == ix) {
#pragma unroll
            for (int j = 8; j > 0; --j) { sk[j] = sk[j - 1]; si[j] = si[j - 1]; }
            sk[0] = -1e300; si[0] = 0x7fffffff;
        }
    }
}

// fused gather-max + MFMA 1x1 conv + bias + ReLU.
__global__ __launch_bounds__(256, 2) void k_gemm(const float* __restrict__ xT,
                                                 const int* __restrict__ idx9,
                                                 const unsigned short* __restrict__ wfrag,
                                                 const float* __restrict__ bias,
                                                 float* __restrict__ out) {
    __shared__ float h[128][65];
    int b  = blockIdx.x & 7;                     // XCD-pinned batch
    int n0 = (blockIdx.x >> 3) * 64;
    int wave = threadIdx.x >> 6, lane = threadIdx.x & 63;

    const short8* fw = (const short8*)wfrag;
    short8 Wh[2][4], Wl[2][4];
#pragma unroll
    for (int t = 0; t < 2; ++t)
#pragma unroll
        for (int kc = 0; kc < 4; ++kc) {
            size_t cb = (size_t)((wave * 2 + t) * 4 + kc) * 2 * 64;
            Wh[t][kc] = fw[cb + lane];
            Wl[t][kc] = fw[cb + 64 + lane];
        }

    for (int r = 0; r < 16; ++r) {
        int nn = wave * 16 + r;
        size_t row = (size_t)b * N_ + n0 + nn;
        const int* id = idx9 + row * KNN;
        float m = -FLT_MAX;
#pragma unroll
        for (int k = 0; k < KNN; ++k) {
            int j = id[k];
            m = fmaxf(m, xT[(((size_t)b << 12) + j) * C_ + lane]);
        }
        float xic = xT[row * C_ + lane];
        h[lane][nn]      = xic;
        h[64 + lane][nn] = m - xic;
    }
    __syncthreads();

    f32x4 acc[2][4];
#pragma unroll
    for (int t = 0; t < 2; ++t)
#pragma unroll
        for (int nt = 0; nt < 4; ++nt) acc[t][nt] = (f32x4){0.f, 0.f, 0.f, 0.f};

    int cb0 = (lane >> 4) * 8;
    int nl  = lane & 15;
#pragma unroll
    for (int kc = 0; kc < 4; ++kc) {
#pragma unroll
        for (int nt = 0; nt < 4; ++nt) {
            short8 bh, bl;
#pragma unroll
            for (int j = 0; j < 8; ++j) {
                float v = h[kc * 32 + cb0 + j][nt * 16 + nl];
                unsigned short hb = f2bf(v);
                bl[j] = (short)f2bf(v - bf2f(hb));
                bh[j] = (short)hb;
            }
#pragma unroll
            for (int t = 0; t < 2; ++t) {
                acc[t][nt] = __builtin_amdgcn_mfma_f32_16x16x32_bf16(Wh[t][kc], bh, acc[t][nt], 0, 0, 0);
                acc[t][nt] = __builtin_amdgcn_mfma_f32_16x16x32_bf16(Wl[t][kc], bh, acc[t][nt], 0, 0, 0);
                acc[t][nt] = __builtin_amdgcn_mfma_f32_16x16x32_bf16(Wh[t][kc], bl, acc[t][nt], 0, 0, 0);
            }
        }
    }
    __syncthreads();   // h reads done; reuse h for output staging

    f32x4 bs[2];
#pragma unroll
    for (int t = 0; t < 2; ++t)
        bs[t] = *(const f32x4*)(bias + wave * 32 + t * 16 + (lane >> 4) * 4);
#pragma unroll
    for (int t = 0; t < 2; ++t)
#pragma unroll
        for (int nt = 0; nt < 4; ++nt)
#pragma unroll
            for (int j = 0; j < 4; ++j) {
                float v = acc[t][nt][j] + bs[t][j];
                h[wave * 32 + t * 16 + (lane >> 4) * 4 + j][nt * 16 + nl] = fmaxf(v, 0.f);
            }
    __syncthreads();

#pragma unroll
    for (int rr = 0; rr < 32; ++rr) {
        int o = wave * 32 + rr;
        out[((size_t)b * OUT_ + o) * N_ + n0 + lane] = h[o][lane];
    }
}

extern "C" void kernel_launch(void* const* d_in, const int* in_sizes, int n_in,
                              void* d_out, int out_size, void* d_ws, size_t ws_size,
                              hipStream_t stream) {
    const float* x    = (const float*)d_in[0];
    const float* W    = (const float*)d_in[1];
    const float* bias = (const float*)d_in[2];
    float* out = (float*)d_out;
    char* ws = (char*)d_ws;

    float*          xT     = (float*)(ws);
    unsigned short* xfrag  = (unsigned short*)(ws + 8388608);
    int*            idx9   = (int*)(ws + 8388608);        // aliases xfrag (dead by refine)
    float*          x2     = (float*)(ws + 16777216);
    unsigned short* wfrag  = (unsigned short*)(ws + 16908288);
    unsigned*       cand48 = (unsigned*)(ws + 16973824);
    int*            cnt4   = (int*)(ws + 23265280);

    k_transpose<<<dim3(520),  dim3(256), 0, stream>>>(x, xT, x2, xfrag, W, wfrag);
    k_topk_mf  <<<dim3(2048), dim3(256), 0, stream>>>(xfrag, x2, cand48, cnt4);
    k_refine   <<<dim3(8192), dim3(256), 0, stream>>>(xT, cand48, cnt4, idx9);
    k_fallback <<<dim3(8192), dim3(256), 0, stream>>>(xT, cnt4, idx9);
    k_gemm     <<<dim3(512),  dim3(256), 0, stream>>>(xT, idx9, wfrag, bias, out);
}

// Round 21
// 99.334 us; speedup vs baseline: 1.3626x; 1.3626x over previous
//
#include <hip/hip_runtime.h>
#include <float.h>

#define B_   8
#define C_   64
#define N_   4096
#define OUT_ 128
#define KNN  9
#define CAP  64          // per-quarter append capacity (overflow -> exact fallback)
#define TAU_A 2.15f      // threshold: tau = TAU_A*sigma_n - 64

typedef __attribute__((ext_vector_type(8))) short short8;
typedef __attribute__((ext_vector_type(4))) float f32x4;

__device__ inline unsigned short f2bf(float f) {
    unsigned u = __float_as_uint(f);
    unsigned r = (u + 0x7fffu + ((u >> 16) & 1u)) >> 16;
    return (unsigned short)r;
}
__device__ inline float bf2f(unsigned short s) {
    return __uint_as_float(((unsigned)s) << 16);
}

// ---------------------------------------------------------------------------
// ws layout (bytes):
//   xT:     [B][N][C] float    @ 0          (8388608)
//   xfrag:  hi bf16 chunks     @ 8388608    (4194304)  } idx9 aliases xfrag
//   idx9:   [B*N][9]  int      @ 8388608    (1179648)  } (xfrag dead by refine)
//   x2:     [B][N]    float    @ 16777216   (131072)
//   wfrag:  W hi/lo bf16 frags @ 16908288   (65536)
//   cand48: [B*N][48] u32      @ 16973824   (6291456)  packed (key20|idx12)
//   cnt4:   [B*N][4]  int      @ 23265280   (524288)   total ~23.8 MB
//
// HARD-WON CONSTRAINTS:
//  - (R12,R16) launch_bounds waves/EU >= 8 caps VGPR at 32 -> scan spills.
//    Use waves/EU == 4 (VGPR cap 64; body measures ~40).
//  - (R18) fullscan fallback must be a SEPARATE early-exit kernel (reg pressure).
// ---------------------------------------------------------------------------

// transpose + x2 + bf16-hi x-fragment build; blocks 512..519 build W frags.
__global__ void k_transpose(const float* __restrict__ x, float* __restrict__ xT,
                            float* __restrict__ x2, unsigned short* __restrict__ xfrag,
                            const float* __restrict__ W, unsigned short* __restrict__ wfrag) {
    __shared__ float t[C_][65];
    int tid = threadIdx.x;
    if (blockIdx.x >= 512) {                     // merged k_wt
        int mt = blockIdx.x - 512;
        int kc = tid >> 6, L = tid & 63;
        int o  = mt * 16 + (L & 15);
        int c0 = kc * 32 + ((L >> 4) * 8);
        const float* src = W + (size_t)o * 128 + c0;
        float4 v0 = *(const float4*)src, v1 = *(const float4*)(src + 4);
        float vs[8] = {v0.x, v0.y, v0.z, v0.w, v1.x, v1.y, v1.z, v1.w};
        short8 hi, lo;
#pragma unroll
        for (int j = 0; j < 8; ++j) {
            unsigned short hb = f2bf(vs[j]);
            float hf = bf2f(hb);
            lo[j] = (short)f2bf(vs[j] - hf);
            hi[j] = (short)hb;
        }
        size_t cb = (size_t)(mt * 4 + kc) * 2 * 512;   // ushort units
        *(short8*)(wfrag + cb + L * 8)       = hi;
        *(short8*)(wfrag + cb + 512 + L * 8) = lo;
        return;
    }
    int b  = blockIdx.x & 7;                     // XCD-pinned batch
    int n0 = (blockIdx.x >> 3) * 64;
    for (int i = 0; i < 4; ++i) {
        int f = i * 256 + tid;
        int c = f >> 4, n4 = f & 15;
        float4 v = *(const float4*)(x + ((size_t)b * C_ + c) * N_ + n0 + n4 * 4);
        t[c][n4 * 4 + 0] = v.x;
        t[c][n4 * 4 + 1] = v.y;
        t[c][n4 * 4 + 2] = v.z;
        t[c][n4 * 4 + 3] = v.w;
    }
    __syncthreads();
    for (int i = 0; i < 4; ++i) {
        int f = i * 256 + tid;
        int n = f >> 4, c4 = f & 15;
        float4 v = {t[c4 * 4 + 0][n], t[c4 * 4 + 1][n],
                    t[c4 * 4 + 2][n], t[c4 * 4 + 3][n]};
        *(float4*)(xT + ((size_t)b * N_ + n0 + n) * C_ + c4 * 4) = v;
    }
    int q = tid >> 6, L = tid & 63;
    int mloc = q * 16 + (L & 15);
    int k8 = (L >> 4) * 8;
    size_t cb = (size_t)(b * 256 + (n0 >> 4) + q) * 2 * 512;   // ushort units
#pragma unroll
    for (int h = 0; h < 2; ++h) {
        short8 hi;
#pragma unroll
        for (int j = 0; j < 8; ++j)
            hi[j] = (short)f2bf(t[h * 32 + k8 + j][mloc]);
        *(short8*)(xfrag + cb + h * 512 + L * 8) = hi;
    }
    if (tid < 64) {
        float s = 0.f;
        for (int c = 0; c < C_; ++c) { float v = t[c][tid]; s += v * v; }
        x2[(size_t)b * N_ + n0 + tid] = s;
    }
}

// append packed (20-bit sortable key | 12-bit index)
#define APPEND(KEY, TAU, LN, MIDX)                                      \
    if ((KEY) > (TAU)) {                                                \
        unsigned u = __float_as_uint(KEY);                              \
        u = (u & 0x80000000u) ? ~u : (u | 0x80000000u);                 \
        unsigned pk = (u & 0xFFFFF000u) | (unsigned)(MIDX);             \
        int sl = atomicAdd(&cnt_s[LN], 1);                              \
        if (sl < CAP) buf_s[LN][sl] = pk;                               \
    }

// MFMA scan (bf16-hi) + threshold compaction + in-LDS per-quarter top-12.
// grid 2048: b = blk&7 (XCD-pinned), mq = (blk>>3)&3, ng = blk>>5.
// lb(256,4): VGPR cap 64 (body ~40, NO spill); small blocks pack tightly.
__global__ __launch_bounds__(256, 4) void k_topk_mf(const unsigned short* __restrict__ xfrag,
                                                    const float* __restrict__ x2,
                                                    unsigned* __restrict__ cand48,
                                                    int* __restrict__ cnt4) {
    __shared__ int cnt_s[64];
    __shared__ unsigned buf_s[64][CAP];
    int b    = blockIdx.x & 7;
    int mq   = (blockIdx.x >> 3) & 3;
    int ng   = blockIdx.x >> 5;                  // 0..63
    int wave = threadIdx.x >> 6, lane = threadIdx.x & 63;
    if (threadIdx.x < 64) cnt_s[threadIdx.x] = 0;

    const short8* fr = (const short8*)xfrag;     // 16B units; chunk = 64 short8

    short8 Bh[4][2];
#pragma unroll
    for (int q = 0; q < 4; ++q)
#pragma unroll
        for (int h = 0; h < 2; ++h) {
            int ch = ((b * 256 + ng * 4 + q) * 2 + h);
            Bh[q][h] = fr[(size_t)ch * 64 + lane];
        }

    float tau[4];
#pragma unroll
    for (int q = 0; q < 4; ++q) {
        float x2n = x2[b * N_ + ng * 64 + q * 16 + (lane & 15)];
        tau[q] = TAU_A * sqrtf(fmaf(4.f, x2n, 128.f)) - 64.f;
    }

    int mt0 = mq * 64 + wave * 16;               // m-tile start (16 tiles per wave)
    const short8* pA = fr + (size_t)(b * 256 + mt0) * 2 * 64 + lane;
    const f32x4*  px2 = (const f32x4*)(x2 + b * N_ + mt0 * 16 + (lane >> 4) * 4);
    short8 Ah0 = pA[0], Ah1 = pA[64];
    f32x4 x2v = *px2;

    __syncthreads();   // cnt_s zeroed

    for (int i = 0; i < 16; ++i) {
        if (i != 15) { pA += 128; px2 += 4; }
        short8 nAh0 = pA[0], nAh1 = pA[64];
        f32x4 nx2 = *px2;

        int mbase = (mt0 + i) * 16 + (lane >> 4) * 4;

#pragma unroll
        for (int q = 0; q < 4; ++q) {
            f32x4 acc = {0.f, 0.f, 0.f, 0.f};
            acc = __builtin_amdgcn_mfma_f32_16x16x32_bf16(Ah0, Bh[q][0], acc, 0, 0, 0);
            acc = __builtin_amdgcn_mfma_f32_16x16x32_bf16(Ah1, Bh[q][1], acc, 0, 0, 0);
            float k0 = fmaf(2.f, acc[0], -x2v[0]);
            float k1 = fmaf(2.f, acc[1], -x2v[1]);
            float k2 = fmaf(2.f, acc[2], -x2v[2]);
            float k3 = fmaf(2.f, acc[3], -x2v[3]);
            float kmax = fmaxf(fmaxf(k0, k1), fmaxf(k2, k3));
            if (kmax > tau[q]) {
                int ln = q * 16 + (lane & 15);
                APPEND(k0, tau[q], ln, mbase + 0)
                APPEND(k1, tau[q], ln, mbase + 1)
                APPEND(k2, tau[q], ln, mbase + 2)
                APPEND(k3, tau[q], ln, mbase + 3)
            }
        }
        Ah0 = nAh0; Ah1 = nAh1; x2v = nx2;
    }

    __syncthreads();
    if (threadIdx.x < 64) {
        int r = threadIdx.x;
        int c = cnt_s[r];
        size_t grow = (size_t)b * N_ + ng * 64 + r;
        cnt4[grow * 4 + mq] = c;
        int cc = min(c, CAP);
        unsigned best[12];
#pragma unroll
        for (int j = 0; j < 12; ++j) best[j] = 0u;
        for (int s = 0; s < cc; ++s) {
            unsigned v = buf_s[r][s];
            if (v > best[0]) {
                best[0] = v;
#pragma unroll
                for (int j = 0; j < 11; ++j) {
                    bool sw = best[j] > best[j + 1];
                    unsigned t = best[j];
                    best[j]     = sw ? best[j + 1] : best[j];
                    best[j + 1] = sw ? t : best[j + 1];
                }
            }
        }
#pragma unroll
        for (int j = 0; j < 12; ++j)
            cand48[grow * 48 + mq * 12 + j] = best[11 - j];
    }
}

// refine: coarse-prefilter 48 -> top-16 by packed u32 key (integer compares),
// then exact fp64 re-rank of the 16 finalists. 4 rows/wave, all 64 lanes busy.
// Coarse keys are globally comparable (same monotone pack); error ~0.15 <<
// rank9->16 key gap (~2+). cnt anomalies still -> exact fallback kernel.
__global__ __launch_bounds__(256) void k_refine(const float* __restrict__ xT,
                                                const unsigned* __restrict__ cand48,
                                                const int* __restrict__ cnt4,
                                                int* __restrict__ idx9) {
    __shared__ unsigned pk_s[4][4][48];
    __shared__ int      fin[4][4][16];
    __shared__ double   kk[4][4][16];
    __shared__ int      ki[4][4][16];
    int wave = threadIdx.x >> 6, lane = threadIdx.x & 63;
    int g = lane >> 4, s = lane & 15;            // group (row), slot
    int b = blockIdx.x & 7;
    int row = b * N_ + (blockIdx.x >> 3) * 16 + wave * 4 + g;

    int c0 = cnt4[(size_t)row * 4 + 0];
    int c1 = cnt4[(size_t)row * 4 + 1];
    int c2 = cnt4[(size_t)row * 4 + 2];
    int c3 = cnt4[(size_t)row * 4 + 3];
    int cmax = max(max(c0, c1), max(c2, c3));
    bool ok = (c0 + c1 + c2 + c3 >= KNN) && (cmax <= CAP);

    fin[wave][g][s] = 0x7fffffff;                // sentinel

    // stage packed keys: lane covers j = s, s+16, s+32
    unsigned mypk[3]; int myj[3];
#pragma unroll
    for (int jj = 0; jj < 3; ++jj) {
        int j = s + jj * 16;
        int qq = j / 12, slot = j - qq * 12;
        int cq = (qq == 0) ? c0 : (qq == 1) ? c1 : (qq == 2) ? c2 : c3;
        bool valid = ok && (slot < min(cq, 12));
        unsigned pk = valid ? cand48[(size_t)row * 48 + j] : 0u;
        pk_s[wave][g][j] = pk;
        mypk[jj] = pk; myj[jj] = j;
    }
    // same-wave LDS write->read (in-order per wave): rank by integer compares
    int rank[3] = {0, 0, 0};
    for (int k = 0; k < 48; ++k) {
        unsigned v = pk_s[wave][g][k];           // 16-lane broadcast read
#pragma unroll
        for (int jj = 0; jj < 3; ++jj) rank[jj] += (v > mypk[jj]) ? 1 : 0;
    }
#pragma unroll
    for (int jj = 0; jj < 3; ++jj)
        if (mypk[jj] != 0u && rank[jj] < 16)
            fin[wave][g][rank[jj]] = (int)(mypk[jj] & 0xFFFu);

    // fp64 re-rank of up to 16 finalists (all lanes active)
    int m = fin[wave][g][s];
    double mykey = -1e300; int myidx = 0x7fffffff;
    if (ok && m != 0x7fffffff) {
        const float* xi = xT + (size_t)row * C_;               // group-broadcast
        const float* xm = xT + (((size_t)b << 12) + m) * C_;   // per-lane stream
        double d0 = 0.0, d1 = 0.0, s0 = 0.0, s1 = 0.0;
#pragma unroll
        for (int c4 = 0; c4 < 16; c4 += 2) {
            float4 a0 = *(const float4*)(xi + c4 * 4);
            float4 a1 = *(const float4*)(xi + c4 * 4 + 4);
            float4 v0 = *(const float4*)(xm + c4 * 4);
            float4 v1 = *(const float4*)(xm + c4 * 4 + 4);
            d0 = fma((double)a0.x, (double)v0.x, d0);  s0 = fma((double)v0.x, (double)v0.x, s0);
            d0 = fma((double)a0.y, (double)v0.y, d0);  s0 = fma((double)v0.y, (double)v0.y, s0);
            d0 = fma((double)a0.z, (double)v0.z, d0);  s0 = fma((double)v0.z, (double)v0.z, s0);
            d0 = fma((double)a0.w, (double)v0.w, d0);  s0 = fma((double)v0.w, (double)v0.w, s0);
            d1 = fma((double)a1.x, (double)v1.x, d1);  s1 = fma((double)v1.x, (double)v1.x, s1);
            d1 = fma((double)a1.y, (double)v1.y, d1);  s1 = fma((double)v1.y, (double)v1.y, s1);
            d1 = fma((double)a1.z, (double)v1.z, d1);  s1 = fma((double)v1.z, (double)v1.z, s1);
            d1 = fma((double)a1.w, (double)v1.w, d1);  s1 = fma((double)v1.w, (double)v1.w, s1);
        }
        mykey = 2.0 * (d0 + d1) - (s0 + s1);
        myidx = m;
    }
    kk[wave][g][s] = mykey; ki[wave][g][s] = myidx;
    if (myidx != 0x7fffffff) {
        int r = 0;
#pragma unroll
        for (int k = 0; k < 16; ++k) {
            double ok2 = kk[wave][g][k]; int oi = ki[wave][g][k];
            r += (ok2 > mykey || (ok2 == mykey && oi < myidx)) ? 1 : 0;
        }
        if (r < KNN) idx9[(size_t)row * KNN + r] = myidx;   // ranks distinct
    }
}

// exact fp64 full scan for rows where the threshold buffers failed (insurance).
// SEPARATE kernel: its register cost must not touch refine's occupancy (R18).
__global__ void k_fallback(const float* __restrict__ xT, const int* __restrict__ cnt4,
                           int* __restrict__ idx9) {
    int wave = threadIdx.x >> 6, lane = threadIdx.x & 63;
    int row = blockIdx.x * 4 + wave;
    int c0 = cnt4[(size_t)row * 4 + 0];
    int c1 = cnt4[(size_t)row * 4 + 1];
    int c2 = cnt4[(size_t)row * 4 + 2];
    int c3 = cnt4[(size_t)row * 4 + 3];
    int cmax = max(max(c0, c1), max(c2, c3));
    if ((c0 + c1 + c2 + c3 >= KNN) && (cmax <= CAP)) return;
    int b = row >> 12;
    const float* xi = xT + (size_t)row * C_;
    float4 xr[16];
#pragma unroll
    for (int c4 = 0; c4 < 16; ++c4) xr[c4] = *(const float4*)(xi + c4 * 4);
    double sk[9]; int si[9];
#pragma unroll
    for (int j = 0; j < 9; ++j) { sk[j] = -1e300; si[j] = 0x7fffffff; }
    for (int mb = 0; mb < N_; mb += 64) {
        int m = mb + lane;
        const float* xm = xT + (((size_t)b << 12) + m) * C_;
        double d0 = 0.0, d1 = 0.0, s0 = 0.0, s1 = 0.0;
#pragma unroll
        for (int c4 = 0; c4 < 16; c4 += 2) {
            float4 v = *(const float4*)(xm + c4 * 4);
            float4 w = *(const float4*)(xm + c4 * 4 + 4);
            float4 a = xr[c4], bb = xr[c4 + 1];
            d0 = fma((double)a.x, (double)v.x, d0);  s0 = fma((double)v.x, (double)v.x, s0);
            d0 = fma((double)a.y, (double)v.y, d0);  s0 = fma((double)v.y, (double)v.y, s0);
            d0 = fma((double)a.z, (double)v.z, d0);  s0 = fma((double)v.z, (double)v.z, s0);
            d0 = fma((double)a.w, (double)v.w, d0);  s0 = fma((double)v.w, (double)v.w, s0);
            d1 = fma((double)bb.x, (double)w.x, d1); s1 = fma((double)w.x, (double)w.x, s1);
            d1 = fma((double)bb.y, (double)w.y, d1); s1 = fma((double)w.y, (double)w.y, s1);
            d1 = fma((double)bb.z, (double)w.z, d1); s1 = fma((double)w.z, (double)w.z, s1);
            d1 = fma((double)bb.w, (double)w.w, d1); s1 = fma((double)w.w, (double)w.w, s1);
        }
        double key = 2.0 * (d0 + d1) - (s0 + s1);
        if (key > sk[0] || (key == sk[0] && m < si[0])) {
            sk[0] = key; si[0] = m;
#pragma unroll
            for (int j = 0; j < 8; ++j) {
                bool sw = (sk[j] > sk[j + 1]) || (sk[j] == sk[j + 1] && si[j] < si[j + 1]);
                double tk = sk[j]; int ti = si[j];
                sk[j]     = sw ? sk[j + 1] : sk[j];
                si[j]     = sw ? si[j + 1] : si[j];
                sk[j + 1] = sw ? tk : sk[j + 1];
                si[j + 1] = sw ? ti : si[j + 1];
            }
        }
    }
    for (int r = 0; r < KNN; ++r) {
        double k = sk[8]; int ix = si[8];
#pragma unroll
        for (int o = 32; o; o >>= 1) {
            double ok = __shfl_xor(k, o); int oi = __shfl_xor(ix, o);
            bool take = (ok > k) || (ok == k && oi < ix);
            k = take ? ok : k; ix = take ? oi : ix;
        }
        if (lane == 0) idx9[(size_t)row * KNN + r] = ix;
        if (si[8] == ix) {
#pragma unroll
            for (int j = 8; j > 0; --j) { sk[j] = sk[j - 1]; si[j] = si[j - 1]; }
            sk[0] = -1e300; si[0] = 0x7fffffff;
        }
    }
}

// fused gather-max + MFMA 1x1 conv + bias + ReLU.
__global__ __launch_bounds__(256, 2) void k_gemm(const float* __restrict__ xT,
                                                 const int* __restrict__ idx9,
                                                 const unsigned short* __restrict__ wfrag,
                                                 const float* __restrict__ bias,
                                                 float* __restrict__ out) {
    __shared__ float h[128][65];
    int b  = blockIdx.x & 7;                     // XCD-pinned batch
    int n0 = (blockIdx.x >> 3) * 64;
    int wave = threadIdx.x >> 6, lane = threadIdx.x & 63;

    const short8* fw = (const short8*)wfrag;
    short8 Wh[2][4], Wl[2][4];
#pragma unroll
    for (int t = 0; t < 2; ++t)
#pragma unroll
        for (int kc = 0; kc < 4; ++kc) {
            size_t cb = (size_t)((wave * 2 + t) * 4 + kc) * 2 * 64;
            Wh[t][kc] = fw[cb + lane];
            Wl[t][kc] = fw[cb + 64 + lane];
        }

    for (int r = 0; r < 16; ++r) {
        int nn = wave * 16 + r;
        size_t row = (size_t)b * N_ + n0 + nn;
        const int* id = idx9 + row * KNN;
        float m = -FLT_MAX;
#pragma unroll
        for (int k = 0; k < KNN; ++k) {
            int j = id[k];
            m = fmaxf(m, xT[(((size_t)b << 12) + j) * C_ + lane]);
        }
        float xic = xT[row * C_ + lane];
        h[lane][nn]      = xic;
        h[64 + lane][nn] = m - xic;
    }
    __syncthreads();

    f32x4 acc[2][4];
#pragma unroll
    for (int t = 0; t < 2; ++t)
#pragma unroll
        for (int nt = 0; nt < 4; ++nt) acc[t][nt] = (f32x4){0.f, 0.f, 0.f, 0.f};

    int cb0 = (lane >> 4) * 8;
    int nl  = lane & 15;
#pragma unroll
    for (int kc = 0; kc < 4; ++kc) {
#pragma unroll
        for (int nt = 0; nt < 4; ++nt) {
            short8 bh, bl;
#pragma unroll
            for (int j = 0; j < 8; ++j) {
                float v = h[kc * 32 + cb0 + j][nt * 16 + nl];
                unsigned short hb = f2bf(v);
                bl[j] = (short)f2bf(v - bf2f(hb));
                bh[j] = (short)hb;
            }
#pragma unroll
            for (int t = 0; t < 2; ++t) {
                acc[t][nt] = __builtin_amdgcn_mfma_f32_16x16x32_bf16(Wh[t][kc], bh, acc[t][nt], 0, 0, 0);
                acc[t][nt] = __builtin_amdgcn_mfma_f32_16x16x32_bf16(Wl[t][kc], bh, acc[t][nt], 0, 0, 0);
                acc[t][nt] = __builtin_amdgcn_mfma_f32_16x16x32_bf16(Wh[t][kc], bl, acc[t][nt], 0, 0, 0);
            }
        }
    }
    __syncthreads();   // h reads done; reuse h for output staging

    f32x4 bs[2];
#pragma unroll
    for (int t = 0; t < 2; ++t)
        bs[t] = *(const f32x4*)(bias + wave * 32 + t * 16 + (lane >> 4) * 4);
#pragma unroll
    for (int t = 0; t < 2; ++t)
#pragma unroll
        for (int nt = 0; nt < 4; ++nt)
#pragma unroll
            for (int j = 0; j < 4; ++j) {
                float v = acc[t][nt][j] + bs[t][j];
                h[wave * 32 + t * 16 + (lane >> 4) * 4 + j][nt * 16 + nl] = fmaxf(v, 0.f);
            }
    __syncthreads();

#pragma unroll
    for (int rr = 0; rr < 32; ++rr) {
        int o = wave * 32 + rr;
        out[((size_t)b * OUT_ + o) * N_ + n0 + lane] = h[o][lane];
    }
}

extern "C" void kernel_launch(void* const* d_in, const int* in_sizes, int n_in,
                              void* d_out, int out_size, void* d_ws, size_t ws_size,
                              hipStream_t stream) {
    const float* x    = (const float*)d_in[0];
    const float* W    = (const float*)d_in[1];
    const float* bias = (const float*)d_in[2];
    float* out = (float*)d_out;
    char* ws = (char*)d_ws;

    float*          xT     = (float*)(ws);
    unsigned short* xfrag  = (unsigned short*)(ws + 8388608);
    int*            idx9   = (int*)(ws + 8388608);        // aliases xfrag (dead by refine)
    float*          x2     = (float*)(ws + 16777216);
    unsigned short* wfrag  = (unsigned short*)(ws + 16908288);
    unsigned*       cand48 = (unsigned*)(ws + 16973824);
    int*            cnt4   = (int*)(ws + 23265280);

    k_transpose<<<dim3(520),  dim3(256), 0, stream>>>(x, xT, x2, xfrag, W, wfrag);
    k_topk_mf  <<<dim3(2048), dim3(256), 0, stream>>>(xfrag, x2, cand48, cnt4);
    k_refine   <<<dim3(2048), dim3(256), 0, stream>>>(xT, cand48, cnt4, idx9);
    k_fallback <<<dim3(8192), dim3(256), 0, stream>>>(xT, cnt4, idx9);
    k_gemm     <<<dim3(512),  dim3(256), 0, stream>>>(xT, idx9, wfrag, bias, out);
}